// Round 15
// baseline (176.267 us; speedup 1.0000x reference)
//
#include <hip/hip_runtime.h>
#include <hip/hip_bf16.h>
#include <math.h>

#define CH 64
#define NPOS 9216   // 96*96
#define NTOT 18432  // 2*9216
#define NSPLIT 16
#define TILES_PER_SPLIT 9   // 9216 / (64 keys * 16 splits)
#define LOG2E 1.4426950408889634f

typedef short bf16x8 __attribute__((ext_vector_type(8)));
typedef short bf16x4 __attribute__((ext_vector_type(4)));
typedef float f32x4 __attribute__((ext_vector_type(4)));
typedef int   i32x4 __attribute__((ext_vector_type(4)));
typedef int   i32x2 __attribute__((ext_vector_type(2)));
typedef unsigned int u32;

__device__ __forceinline__ float bf2f(short s) {
  unsigned int u = ((unsigned int)(unsigned short)s) << 16;
  return __builtin_bit_cast(float, u);
}
__device__ __forceinline__ short f2bf(float f) {
  unsigned int u = __builtin_bit_cast(unsigned int, f);
  unsigned int r = (u + 0x7fffu + ((u >> 16) & 1u)) >> 16;  // RNE
  return (short)r;
}
__device__ __forceinline__ float gelu_exact(float x) {
  return 0.5f * x * (1.f + erff(x * 0.70710678118654752440f));
}

// R32: the last untested structural lever — k_attn 1024-thr / 512-Q blocks
// (R21's rounds-halving lever, second notch). Rounds 10368 -> 5184; staging =
// ONE i32x4/thread (waves 0-7 stage K, waves 8-15 stage V); resident waves/CU
// -> hardware cap 32 (2 blocks x 16 waves). NSPLIT 12->16 (TILES=9) keeps
// grid at 576 blocks. PoT 28.3->37.7MB (+~3us in k_res, accepted).
// Discriminates the residual attn model: barrier cost ~ rounds (win) vs
// ~ rounds x width (invariant -> attn closed). Tail kernels = R31 forms.

// ---------------- Kernel A: LN1 + MFMA QKV projection ----------------
// grid (576) x 256. 32 pos/block. Q/K -> [n][c]; V -> TRANSPOSED [c][n].
__global__ __launch_bounds__(256) void k_ln_qkv(
    const float* __restrict__ x, const float* __restrict__ ln1w, const float* __restrict__ ln1b,
    const float* __restrict__ qw, const float* __restrict__ qb,
    const float* __restrict__ kw, const float* __restrict__ kb,
    const float* __restrict__ vw, const float* __restrict__ vb,
    short* __restrict__ Qg, short* __restrict__ Kg, short* __restrict__ Vgt) {
  __shared__ float s1a[256], s2a[256];
  __shared__ __align__(16) short xn[32 * 72];
  int t = threadIdx.x;
  int w8 = t >> 5;     // channel octet 0..7
  int p = t & 31;      // position in block
  int q0 = blockIdx.x * 32;
  int q = q0 + p;
  int b = q / NPOS;
  int nn = q0 % NPOS;
  int n = q % NPOS;

  const float* xb = x + (size_t)b * CH * NPOS + n;
  float xr[8];
  float s1 = 0.f, s2 = 0.f;
#pragma unroll
  for (int cl = 0; cl < 8; ++cl) {
    float v = xb[(size_t)(w8 * 8 + cl) * NPOS];
    xr[cl] = v;
    s1 += v;
    s2 += v * v;
  }
  s1a[w8 * 32 + p] = s1;
  s2a[w8 * 32 + p] = s2;
  __syncthreads();
  float mu = 0.f, m2 = 0.f;
#pragma unroll
  for (int ww = 0; ww < 8; ++ww) { mu += s1a[ww * 32 + p]; m2 += s2a[ww * 32 + p]; }
  mu *= (1.f / 64.f);
  float var = m2 * (1.f / 64.f) - mu * mu;
  float rstd = rsqrtf(var + 1e-5f);
  {
    u32* xw = (u32*)xn;
#pragma unroll
    for (int j2 = 0; j2 < 4; ++j2) {
      int cl = 2 * j2, c = w8 * 8 + cl;
      float y0 = (xr[cl] - mu) * rstd * ln1w[c] + ln1b[c];
      float y1 = (xr[cl + 1] - mu) * rstd * ln1w[c + 1] + ln1b[c + 1];
      u32 pk = ((u32)(unsigned short)f2bf(y1) << 16) | (u32)(unsigned short)f2bf(y0);
      xw[p * 36 + w8 * 4 + j2] = pk;
    }
  }
  __syncthreads();
  int lane = t & 63;
  int L = lane & 15, quad = lane >> 4;
  int cs = t >> 6;   // warp = out-channel strip 0..3
  // B fragments (shared across the 3 matrices)
  bf16x8 b0[2], b1[2];
#pragma unroll
  for (int ps = 0; ps < 2; ++ps) {
    b0[ps] = *(const bf16x8*)(xn + (ps * 16 + L) * 72 + quad * 8);
    b1[ps] = *(const bf16x8*)(xn + (ps * 16 + L) * 72 + 32 + quad * 8);
  }
#pragma unroll
  for (int m = 0; m < 3; ++m) {
    const float* wsrc = (m == 0) ? qw : (m == 1) ? kw : vw;
    const float* bsrc = (m == 0) ? qb : (m == 1) ? kb : vb;
    bf16x8 a0, a1;
    {
      const float* wr = wsrc + (cs * 16 + L) * 64 + quad * 8;
#pragma unroll
      for (int j = 0; j < 8; ++j) { a0[j] = f2bf(wr[j]); a1[j] = f2bf(wr[32 + j]); }
    }
    float bi[4];
#pragma unroll
    for (int i = 0; i < 4; ++i) bi[i] = bsrc[cs * 16 + quad * 4 + i];
#pragma unroll
    for (int ps = 0; ps < 2; ++ps) {
      f32x4 acc = {bi[0], bi[1], bi[2], bi[3]};
      acc = __builtin_amdgcn_mfma_f32_16x16x32_bf16(a0, b0[ps], acc, 0, 0, 0);
      acc = __builtin_amdgcn_mfma_f32_16x16x32_bf16(a1, b1[ps], acc, 0, 0, 0);
      int idx = b * NPOS + nn + ps * 16 + L;
      if (m == 0) {
#pragma unroll
        for (int i = 0; i < 4; ++i)
          Qg[(size_t)idx * 64 + cs * 16 + quad * 4 + i] = f2bf(acc[i]);
      } else if (m == 1) {
#pragma unroll
        for (int i = 0; i < 4; ++i)
          Kg[(size_t)idx * 64 + cs * 16 + quad * 4 + i] = f2bf(acc[i] * LOG2E);
      } else {
#pragma unroll
        for (int i = 0; i < 4; ++i)
          Vgt[(size_t)(cs * 16 + quad * 4 + i) * NTOT + idx] = f2bf(acc[i]);
      }
    }
  }
}

// ---------------- Kernel B: MFMA flash attention (1024 thr / 512 Q, NSPLIT=16) ---------
// grid (18, 2, NSPLIT) x 1024. 512 q/block, 32 q/wave, 16 waves share one tile.
// Staging: waves 0-7 load K (one i32x4/thread), waves 8-15 load V.
#define LDPK 80
#define LDP  72
__global__ __launch_bounds__(1024) void k_attn(
    const short* __restrict__ Qg, const short* __restrict__ Kg, const short* __restrict__ Vgt,
    u32* __restrict__ PoT, float* __restrict__ Pl) {
  __shared__ __align__(16) short Kt[2][64 * LDPK];   // 10240 B each
  __shared__ __align__(16) short Vt[2][64 * LDP];    //  9216 B each -> 38912 total
  int b = blockIdx.y;
  int n0 = blockIdx.x * 512;
  int ks = blockIdx.z;
  int tid = threadIdx.x;
  int w = tid >> 6, lane = tid & 63;
  int L = lane & 15, quad = lane >> 4;

  bf16x8 qa[2][2];
#pragma unroll
  for (int qt = 0; qt < 2; ++qt) {
    const short* qb_ = Qg + ((size_t)(b * NPOS + n0 + w * 32 + qt * 16 + L)) * 64;
    qa[qt][0] = *(const bf16x8*)(qb_ + quad * 8);
    qa[qt][1] = *(const bf16x8*)(qb_ + 32 + quad * 8);
  }

  f32x4 o[2][4];
#pragma unroll
  for (int qt = 0; qt < 2; ++qt)
#pragma unroll
    for (int nb = 0; nb < 4; ++nb) o[qt][nb] = (f32x4){0.f, 0.f, 0.f, 0.f};
  float rl[2] = {0.f, 0.f};

  // staging maps: ONE i32x4 per thread. tid<512: K chunk; tid>=512: V chunk.
  int stid = tid & 511;
  bool isK = tid < 512;
  int ck = stid & 7, rk = stid >> 3;   // K: row rk 0..63, 16B chunk ck
  int c8 = stid & 7, dr = stid >> 3;   // V: channel dr 0..63, phys keys c8*8..+7
  // V slot permutation (32-key windows, 2 per tile): phys key p=h*16+r ->
  // slot (r>>2)*8+h*4+(r&3); keys c8*8..+7 -> vslot..+3 and vslot+8..+11.
  int vslot = (c8 >> 2) * 32 + (c8 & 1) * 16 + ((c8 >> 1) & 1) * 4;
  i32x4 sr;
  // load tile 0 and stage into buffer 0
  {
    int kt = ks * TILES_PER_SPLIT;
    if (isK) {
      sr = ((const i32x4*)(Kg + ((size_t)(b * NPOS + kt * 64)) * 64))[stid];
      ((i32x4*)Kt[0])[rk * 10 + ck] = sr;
    } else {
      sr = *(const i32x4*)(Vgt + (size_t)b * NPOS + kt * 64 + c8 * 8 + (size_t)dr * NTOT);
      short* vrow = Vt[0] + dr * LDP + vslot;
      *(i32x2*)(vrow) = (i32x2){sr[0], sr[1]};
      *(i32x2*)(vrow + 8) = (i32x2){sr[2], sr[3]};
    }
  }

  for (int t = 0; t < TILES_PER_SPLIT; ++t) {
    int cur = t & 1;
    // issue next-tile global load (in flight across the barrier + compute)
    if (t + 1 < TILES_PER_SPLIT) {
      int kt = ks * TILES_PER_SPLIT + t + 1;
      if (isK)
        sr = ((const i32x4*)(Kg + ((size_t)(b * NPOS + kt * 64)) * 64))[stid];
      else
        sr = *(const i32x4*)(Vgt + (size_t)b * NPOS + kt * 64 + c8 * 8 + (size_t)dr * NTOT);
    }
    __syncthreads();   // buf[cur] fully staged (by prev iteration / preamble)

    const i32x4* kt4 = (const i32x4*)Kt[cur];
    const short* vt = Vt[cur];
    auto compute_win = [&](int kp) {
      u32 pw0[4], pw1[4];
#pragma unroll
      for (int h = 0; h < 2; ++h) {
        int kti = kp * 2 + h;
        bf16x8 kf0 = __builtin_bit_cast(bf16x8, kt4[(kti * 16 + L) * 10 + quad]);
        bf16x8 kf1 = __builtin_bit_cast(bf16x8, kt4[(kti * 16 + L) * 10 + 4 + quad]);
#pragma unroll
        for (int qt = 0; qt < 2; ++qt) {
          f32x4 st = {0.f, 0.f, 0.f, 0.f};
          st = __builtin_amdgcn_mfma_f32_16x16x32_bf16(kf0, qa[qt][0], st, 0, 0, 0);
          st = __builtin_amdgcn_mfma_f32_16x16x32_bf16(kf1, qa[qt][1], st, 0, 0, 0);
          float p0 = __builtin_amdgcn_exp2f(st[0]);
          float p1 = __builtin_amdgcn_exp2f(st[1]);
          float p2 = __builtin_amdgcn_exp2f(st[2]);
          float p3 = __builtin_amdgcn_exp2f(st[3]);
          rl[qt] += (p0 + p1) + (p2 + p3);
          u32 lo = __builtin_amdgcn_perm(__builtin_bit_cast(u32, p1), __builtin_bit_cast(u32, p0), 0x07060302u);
          u32 hi = __builtin_amdgcn_perm(__builtin_bit_cast(u32, p3), __builtin_bit_cast(u32, p2), 0x07060302u);
          if (qt == 0) { pw0[h * 2] = lo; pw0[h * 2 + 1] = hi; }
          else         { pw1[h * 2] = lo; pw1[h * 2 + 1] = hi; }
        }
      }
      i32x4 pq0 = {(int)pw0[0], (int)pw0[1], (int)pw0[2], (int)pw0[3]};
      i32x4 pq1 = {(int)pw1[0], (int)pw1[1], (int)pw1[2], (int)pw1[3]};
      bf16x8 pp0 = __builtin_bit_cast(bf16x8, pq0);
      bf16x8 pp1 = __builtin_bit_cast(bf16x8, pq1);
#pragma unroll
      for (int nb = 0; nb < 4; ++nb) {
        bf16x8 va8 = *(const bf16x8*)(vt + (nb * 16 + L) * LDP + kp * 32 + quad * 8);
        o[0][nb] = __builtin_amdgcn_mfma_f32_16x16x32_bf16(va8, pp0, o[0][nb], 0, 0, 0);
        o[1][nb] = __builtin_amdgcn_mfma_f32_16x16x32_bf16(va8, pp1, o[1][nb], 0, 0, 0);
      }
    };

    __builtin_amdgcn_s_setprio(1);
    compute_win(0);
    __builtin_amdgcn_s_setprio(0);

    // stage next tile into the OTHER buffer between the two compute windows
    if (t + 1 < TILES_PER_SPLIT) {
      int nxt = 1 - cur;
      if (isK) {
        ((i32x4*)Kt[nxt])[rk * 10 + ck] = sr;
      } else {
        short* vrow = Vt[nxt] + dr * LDP + vslot;
        *(i32x2*)(vrow) = (i32x2){sr[0], sr[1]};
        *(i32x2*)(vrow + 8) = (i32x2){sr[2], sr[3]};
      }
    }

    __builtin_amdgcn_s_setprio(1);
    compute_win(1);
    __builtin_amdgcn_s_setprio(0);
  }

#pragma unroll
  for (int qt = 0; qt < 2; ++qt) {
    rl[qt] += __shfl_xor(rl[qt], 16);
    rl[qt] += __shfl_xor(rl[qt], 32);
  }

#pragma unroll
  for (int qt = 0; qt < 2; ++qt) {
    int qg = b * NPOS + n0 + w * 32 + qt * 16 + L;
#pragma unroll
    for (int nb = 0; nb < 4; ++nb)
#pragma unroll
      for (int ip = 0; ip < 2; ++ip) {
        u32 pk = ((u32)(unsigned short)f2bf(o[qt][nb][2 * ip + 1]) << 16) |
                 (u32)(unsigned short)f2bf(o[qt][nb][2 * ip]);
        int d32 = nb * 8 + quad * 2 + ip;
        PoT[((size_t)(ks * 32 + d32)) * NTOT + qg] = pk;
      }
    if (quad == 0) Pl[(size_t)ks * NTOT + qg] = rl[qt];
  }
}

// ---------------- Kernel C: merge + residual + LN2 + MFMA proj_in (+X2) ----------------
// R29 form: grid (576) x 256, vectorized merge (NSPLIT i32x4 PoT + 2 f32x4 x).
__global__ __launch_bounds__(256) void k_res_ln2_proj(
    const float* __restrict__ x, const u32* __restrict__ PoT, const float* __restrict__ Pl,
    const float* __restrict__ ln2w, const float* __restrict__ ln2b,
    const float* __restrict__ piw,
    float* __restrict__ X2, float* __restrict__ Hbuf) {
  __shared__ float s1a[32 * 32], s2a[32 * 32];
  __shared__ float inva[32], mua[32], rsa[32];
  __shared__ __align__(16) short xn[32 * 72];
  int t = threadIdx.x;
  int q0 = blockIdx.x * 32;
  int b = q0 / NPOS;
  int nn = q0 % NPOS;

  // phase 0: per-position 1/l
  if (t < 32) {
    float ls = 0.f;
#pragma unroll
    for (int s = 0; s < NSPLIT; ++s) ls += Pl[(size_t)s * NTOT + q0 + t];
    inva[t] = 1.f / ls;
  }
  __syncthreads();

  int rho = t >> 3;       // PoT row 0..31 -> channels 2rho, 2rho+1
  int p4 = (t & 7) * 4;   // 4 consecutive positions
  int c0 = rho * 2;

  float aL[4] = {0.f, 0.f, 0.f, 0.f}, aH[4] = {0.f, 0.f, 0.f, 0.f};
#pragma unroll
  for (int s = 0; s < NSPLIT; ++s) {
    i32x4 v = *(const i32x4*)(PoT + (size_t)(s * 32 + rho) * NTOT + q0 + p4);
#pragma unroll
    for (int i = 0; i < 4; ++i) {
      u32 u = (u32)v[i];
      aL[i] += __builtin_bit_cast(float, u << 16);
      aH[i] += __builtin_bit_cast(float, u & 0xffff0000u);
    }
  }
  f32x4 x0 = *(const f32x4*)(x + (size_t)b * CH * NPOS + (size_t)c0 * NPOS + nn + p4);
  f32x4 x1 = *(const f32x4*)(x + (size_t)b * CH * NPOS + (size_t)(c0 + 1) * NPOS + nn + p4);
  float v0[4], v1[4];
  f32x4 ps1, ps2;
#pragma unroll
  for (int i = 0; i < 4; ++i) {
    float iv = inva[p4 + i];
    v0[i] = x0[i] + aL[i] * iv;
    v1[i] = x1[i] + aH[i] * iv;
    ps1[i] = v0[i] + v1[i];
    ps2[i] = v0[i] * v0[i] + v1[i] * v1[i];
  }
  *(f32x4*)&s1a[rho * 32 + p4] = ps1;
  *(f32x4*)&s2a[rho * 32 + p4] = ps2;
  {
    float* xo = X2 + (size_t)b * CH * NPOS + nn + p4;
    *(f32x4*)(xo + (size_t)c0 * NPOS) = (f32x4){v0[0], v0[1], v0[2], v0[3]};
    *(f32x4*)(xo + (size_t)(c0 + 1) * NPOS) = (f32x4){v1[0], v1[1], v1[2], v1[3]};
  }
  __syncthreads();
  if (t < 32) {
    float m = 0.f, m2 = 0.f;
#pragma unroll
    for (int r = 0; r < 32; ++r) { m += s1a[r * 32 + t]; m2 += s2a[r * 32 + t]; }
    m *= (1.f / 64.f);
    float var = m2 * (1.f / 64.f) - m * m;
    mua[t] = m;
    rsa[t] = rsqrtf(var + 1e-5f);
  }
  __syncthreads();
  {
    u32* xw = (u32*)xn;
    float w0 = ln2w[c0], w1 = ln2w[c0 + 1];
    float bb0 = ln2b[c0], bb1 = ln2b[c0 + 1];
#pragma unroll
    for (int i = 0; i < 4; ++i) {
      int p = p4 + i;
      float mu = mua[p], rs = rsa[p];
      float y0 = (v0[i] - mu) * rs * w0 + bb0;
      float y1 = (v1[i] - mu) * rs * w1 + bb1;
      xw[p * 36 + rho] = ((u32)(unsigned short)f2bf(y1) << 16) | (u32)(unsigned short)f2bf(y0);
    }
  }
  __syncthreads();
  int lane = t & 63;
  int L = lane & 15, quad = lane >> 4;
  int cs = t >> 6;   // warp = channel strip 0..3
  bf16x8 a0, a1;
  {
    const float* wr = piw + (cs * 16 + L) * 64 + quad * 8;
#pragma unroll
    for (int j = 0; j < 8; ++j) { a0[j] = f2bf(wr[j]); a1[j] = f2bf(wr[32 + j]); }
  }
  float* hb = Hbuf + (size_t)b * CH * NPOS + nn;
#pragma unroll
  for (int ps = 0; ps < 2; ++ps) {
    bf16x8 b0 = *(const bf16x8*)(xn + (ps * 16 + L) * 72 + quad * 8);
    bf16x8 b1 = *(const bf16x8*)(xn + (ps * 16 + L) * 72 + 32 + quad * 8);
    f32x4 acc = {0.f, 0.f, 0.f, 0.f};
    acc = __builtin_amdgcn_mfma_f32_16x16x32_bf16(a0, b0, acc, 0, 0, 0);
    acc = __builtin_amdgcn_mfma_f32_16x16x32_bf16(a1, b1, acc, 0, 0, 0);
#pragma unroll
    for (int i = 0; i < 4; ++i)
      hb[(size_t)(cs * 16 + quad * 4 + i) * NPOS + ps * 16 + L] = acc[i];
  }
}

// ---------------- Kernel D: per-patch circular conv (spatial kernel built inline) -------
// R31 form: grid (6, 64, 2) x 192 — 2 bands/block, kl shared.
#define LDB 100
__global__ __launch_bounds__(192) void k_conv(
    float* __restrict__ Hbuf, const float* __restrict__ fftw) {
  __shared__ __align__(16) float band[2][8 * LDB];
  __shared__ float kl[64];
  int c = blockIdx.y, b = blockIdx.z;
  int t = threadIdx.x;
  int g = t / 96, tt = t % 96;
  int hb = blockIdx.x * 2 + g;
  float* base = Hbuf + (size_t)(b * CH + c) * NPOS + hb * 8 * 96;
  // build spatial kernel: k_c = irfft2(hermitian-ext(w_c)) via cosine sum
  if (t < 64) {
    int dp = t >> 3, dq = t & 7;
    const float r = 0.70710678118654752440f;
    const float CO[8] = {1.f, r, 0.f, -r, -1.f, -r, 0.f, r};
    const float* wc = fftw + c * 40;
    float acc = 0.f;
#pragma unroll
    for (int u = 0; u < 8; ++u) {
#pragma unroll
      for (int v = 0; v < 8; ++v) {
        float wv = (v <= 4) ? wc[u * 5 + v] : wc[((8 - u) & 7) * 5 + (8 - v)];
        acc += wv * CO[(u * dp + v * dq) & 7];
      }
    }
    kl[t] = acc * (1.f / 64.f);
  }
  // stage band: within band g, thread tt loads floats tt*8..tt*8+7
  {
    int sr = tt / 12, sc = (tt % 12) * 8;
    f32x4 a = *(const f32x4*)(base + sr * 96 + sc);
    f32x4 d = *(const f32x4*)(base + sr * 96 + sc + 4);
    *(f32x4*)&band[g][sr * LDB + sc] = a;
    *(f32x4*)&band[g][sr * LDB + sc + 4] = d;
  }
  __syncthreads();
  int p = tt / 12, wb = tt % 12;
  float out[8] = {0.f, 0.f, 0.f, 0.f, 0.f, 0.f, 0.f, 0.f};
#pragma unroll
  for (int dp = 0; dp < 8; ++dp) {
    int rr = (p - dp) & 7;
    f32x4 a = *(const f32x4*)&band[g][rr * LDB + wb * 8];
    f32x4 d = *(const f32x4*)&band[g][rr * LDB + wb * 8 + 4];
    float v[8] = {a[0], a[1], a[2], a[3], d[0], d[1], d[2], d[3]};
    const float* krow = &kl[dp * 8];
#pragma unroll
    for (int dq = 0; dq < 8; ++dq) {
      float kv = krow[dq];
#pragma unroll
      for (int q = 0; q < 8; ++q) out[q] += kv * v[(q - dq) & 7];
    }
  }
  __syncthreads();   // all reads done before in-place overwrite
  f32x4 w0 = {out[0], out[1], out[2], out[3]};
  f32x4 w1 = {out[4], out[5], out[6], out[7]};
  *(f32x4*)(base + p * 96 + wb * 8) = w0;
  *(f32x4*)(base + p * 96 + wb * 8 + 4) = w1;
}

// ---------------- Kernel E1: dwconv3x3 + gelu-gate -> G ----------------
// R30 form: grid (18, 32) x 256, 4 pos/thread, branchless x-edges.
__global__ __launch_bounds__(256) void k_dw_gate(
    const float* __restrict__ Hbuf, const float* __restrict__ dww,
    float* __restrict__ G) {
  int cc = blockIdx.y;
  int q4 = (blockIdx.x * 256 + threadIdx.x) * 4;
  int b = q4 / NPOS, n = q4 % NPOS;
  int y = n / 96, x0 = n % 96;
  const float* h1 = Hbuf + (size_t)(b * CH + cc) * NPOS;
  const float* h2 = Hbuf + (size_t)(b * CH + cc + 32) * NPOS;
  float wd1[9], wd2[9];
#pragma unroll
  for (int ki = 0; ki < 9; ++ki) { wd1[ki] = dww[cc * 9 + ki]; wd2[ki] = dww[(cc + 32) * 9 + ki]; }
  f32x4 d1 = {0.f, 0.f, 0.f, 0.f}, d2 = {0.f, 0.f, 0.f, 0.f};
#pragma unroll
  for (int dy = -1; dy <= 1; ++dy) {
    int yy = y + dy;
    if (yy < 0 || yy >= 96) continue;
    const float* r1 = h1 + yy * 96 + x0;
    const float* r2 = h2 + yy * 96 + x0;
    f32x4 c1 = *(const f32x4*)r1;
    f32x4 c2 = *(const f32x4*)r2;
    float l1 = (x0 > 0) ? r1[-1] : 0.f;
    float l2 = (x0 > 0) ? r2[-1] : 0.f;
    float rr1 = (x0 + 4 < 96) ? r1[4] : 0.f;
    float rr2 = (x0 + 4 < 96) ? r2[4] : 0.f;
    int kb = (dy + 1) * 3;
    f32x4 L1 = {l1, c1[0], c1[1], c1[2]};
    f32x4 R1 = {c1[1], c1[2], c1[3], rr1};
    f32x4 L2 = {l2, c2[0], c2[1], c2[2]};
    f32x4 R2 = {c2[1], c2[2], c2[3], rr2};
    d1 += L1 * wd1[kb] + c1 * wd1[kb + 1] + R1 * wd1[kb + 2];
    d2 += L2 * wd2[kb] + c2 * wd2[kb + 1] + R2 * wd2[kb + 2];
  }
  f32x4 gv;
#pragma unroll
  for (int i = 0; i < 4; ++i) gv[i] = gelu_exact(d1[i]) * d2[i];
  *(f32x4*)(G + (size_t)cc * NTOT + q4) = gv;
}

// ---------------- Kernel E2: proj_out + residual ----------------
// R31 form: grid (18, 16) x 256, 4 pos/thread, f32x4 G loads.
__global__ __launch_bounds__(256) void k_proj_out(
    const float* __restrict__ G, const float* __restrict__ poww,
    const float* __restrict__ X2, float* __restrict__ out) {
  int og = blockIdx.y;
  int q4 = (blockIdx.x * 256 + threadIdx.x) * 4;
  int b = q4 / NPOS, n = q4 % NPOS;
  const float* xr = X2 + (size_t)b * CH * NPOS + n;
  float* ob = out + (size_t)b * CH * NPOS + n;
  f32x4 acc[4];
#pragma unroll
  for (int j = 0; j < 4; ++j)
    acc[j] = *(const f32x4*)(xr + (size_t)(og * 4 + j) * NPOS);
#pragma unroll
  for (int cg = 0; cg < 32; ++cg) {
    f32x4 gv = *(const f32x4*)(G + (size_t)cg * NTOT + q4);
#pragma unroll
    for (int j = 0; j < 4; ++j)
      acc[j] += poww[(og * 4 + j) * 32 + cg] * gv;
  }
#pragma unroll
  for (int j = 0; j < 4; ++j)
    *(f32x4*)(ob + (size_t)(og * 4 + j) * NPOS) = acc[j];
}

extern "C" void kernel_launch(void* const* d_in, const int* in_sizes, int n_in,
                              void* d_out, int out_size, void* d_ws, size_t ws_size,
                              hipStream_t stream) {
  const float* x    = (const float*)d_in[0];
  const float* ln1w = (const float*)d_in[1];
  const float* ln1b = (const float*)d_in[2];
  const float* ln2w = (const float*)d_in[3];
  const float* ln2b = (const float*)d_in[4];
  const float* qw   = (const float*)d_in[5];
  const float* qb   = (const float*)d_in[6];
  const float* kw   = (const float*)d_in[7];
  const float* kb   = (const float*)d_in[8];
  const float* vw   = (const float*)d_in[9];
  const float* vb   = (const float*)d_in[10];
  const float* fftw = (const float*)d_in[11];
  const float* piw  = (const float*)d_in[12];
  const float* dww  = (const float*)d_in[13];
  const float* poww = (const float*)d_in[14];

  short* Qg  = (short*)d_ws;
  short* Kg  = Qg + (size_t)NTOT * 64;
  short* Vgt = Kg + (size_t)NTOT * 64;
  u32*   PoT = (u32*)(Vgt + (size_t)NTOT * 64);
  float* Pl  = (float*)(PoT + (size_t)NSPLIT * 32 * NTOT);
  float* X2  = Pl + (size_t)NSPLIT * NTOT;
  float* Hbuf = X2 + (size_t)NTOT * 64;
  float* G   = Hbuf + (size_t)NTOT * 64;

  k_ln_qkv<<<dim3(576), 256, 0, stream>>>(x, ln1w, ln1b, qw, qb, kw, kb, vw, vb, Qg, Kg, Vgt);
  k_attn<<<dim3(18, 2, NSPLIT), 1024, 0, stream>>>(Qg, Kg, Vgt, PoT, Pl);
  k_res_ln2_proj<<<dim3(576), 256, 0, stream>>>(x, PoT, Pl, ln2w, ln2b, piw, X2, Hbuf);
  k_conv<<<dim3(6, 64, 2), 192, 0, stream>>>(Hbuf, fftw);
  k_dw_gate<<<dim3(18, 32), 256, 0, stream>>>(Hbuf, dww, G);
  k_proj_out<<<dim3(18, 16), 256, 0, stream>>>(G, poww, X2, (float*)d_out);
}

// Round 16
// 163.830 us; speedup vs baseline: 1.0759x; 1.0759x over previous
//
#include <hip/hip_runtime.h>
#include <hip/hip_bf16.h>
#include <math.h>

#define CH 64
#define NPOS 9216   // 96*96
#define NTOT 18432  // 2*9216
#define NSPLIT 12
#define TILES_PER_SPLIT 12   // 9216 / (64 keys * 12 splits)
#define LOG2E 1.4426950408889634f

typedef short bf16x8 __attribute__((ext_vector_type(8)));
typedef short bf16x4 __attribute__((ext_vector_type(4)));
typedef float f32x4 __attribute__((ext_vector_type(4)));
typedef int   i32x4 __attribute__((ext_vector_type(4)));
typedef int   i32x2 __attribute__((ext_vector_type(2)));
typedef unsigned int u32;

__device__ __forceinline__ float bf2f(short s) {
  unsigned int u = ((unsigned int)(unsigned short)s) << 16;
  return __builtin_bit_cast(float, u);
}
__device__ __forceinline__ short f2bf(float f) {
  unsigned int u = __builtin_bit_cast(unsigned int, f);
  unsigned int r = (u + 0x7fffu + ((u >> 16) & 1u)) >> 16;  // RNE
  return (short)r;
}
__device__ __forceinline__ float gelu_exact(float x) {
  return 0.5f * x * (1.f + erff(x * 0.70710678118654752440f));
}

// R33: REVERT to R31 (best verified ~165us). R32's 1024-thr attn experiment
// regressed (52.9 -> 65.5us): barrier cost ~ width x rounds, so the block-width
// curve is fully mapped (256t=76, 512t=53 optimum, 1024t=65). k_attn closed.
// Tail fully probed: 2 real fixes (MFMA qkv -20, vec dwconv -4), 6 nulls.
// This is the plateau configuration for this decomposition.

// ---------------- Kernel A: LN1 + MFMA QKV projection ----------------
// grid (576) x 256. 32 pos/block. Q/K -> [n][c]; V -> TRANSPOSED [c][n].
__global__ __launch_bounds__(256) void k_ln_qkv(
    const float* __restrict__ x, const float* __restrict__ ln1w, const float* __restrict__ ln1b,
    const float* __restrict__ qw, const float* __restrict__ qb,
    const float* __restrict__ kw, const float* __restrict__ kb,
    const float* __restrict__ vw, const float* __restrict__ vb,
    short* __restrict__ Qg, short* __restrict__ Kg, short* __restrict__ Vgt) {
  __shared__ float s1a[256], s2a[256];
  __shared__ __align__(16) short xn[32 * 72];
  int t = threadIdx.x;
  int w8 = t >> 5;     // channel octet 0..7
  int p = t & 31;      // position in block
  int q0 = blockIdx.x * 32;
  int q = q0 + p;
  int b = q / NPOS;
  int nn = q0 % NPOS;
  int n = q % NPOS;

  const float* xb = x + (size_t)b * CH * NPOS + n;
  float xr[8];
  float s1 = 0.f, s2 = 0.f;
#pragma unroll
  for (int cl = 0; cl < 8; ++cl) {
    float v = xb[(size_t)(w8 * 8 + cl) * NPOS];
    xr[cl] = v;
    s1 += v;
    s2 += v * v;
  }
  s1a[w8 * 32 + p] = s1;
  s2a[w8 * 32 + p] = s2;
  __syncthreads();
  float mu = 0.f, m2 = 0.f;
#pragma unroll
  for (int ww = 0; ww < 8; ++ww) { mu += s1a[ww * 32 + p]; m2 += s2a[ww * 32 + p]; }
  mu *= (1.f / 64.f);
  float var = m2 * (1.f / 64.f) - mu * mu;
  float rstd = rsqrtf(var + 1e-5f);
  {
    u32* xw = (u32*)xn;
#pragma unroll
    for (int j2 = 0; j2 < 4; ++j2) {
      int cl = 2 * j2, c = w8 * 8 + cl;
      float y0 = (xr[cl] - mu) * rstd * ln1w[c] + ln1b[c];
      float y1 = (xr[cl + 1] - mu) * rstd * ln1w[c + 1] + ln1b[c + 1];
      u32 pk = ((u32)(unsigned short)f2bf(y1) << 16) | (u32)(unsigned short)f2bf(y0);
      xw[p * 36 + w8 * 4 + j2] = pk;
    }
  }
  __syncthreads();
  int lane = t & 63;
  int L = lane & 15, quad = lane >> 4;
  int cs = t >> 6;   // warp = out-channel strip 0..3
  // B fragments (shared across the 3 matrices)
  bf16x8 b0[2], b1[2];
#pragma unroll
  for (int ps = 0; ps < 2; ++ps) {
    b0[ps] = *(const bf16x8*)(xn + (ps * 16 + L) * 72 + quad * 8);
    b1[ps] = *(const bf16x8*)(xn + (ps * 16 + L) * 72 + 32 + quad * 8);
  }
#pragma unroll
  for (int m = 0; m < 3; ++m) {
    const float* wsrc = (m == 0) ? qw : (m == 1) ? kw : vw;
    const float* bsrc = (m == 0) ? qb : (m == 1) ? kb : vb;
    bf16x8 a0, a1;
    {
      const float* wr = wsrc + (cs * 16 + L) * 64 + quad * 8;
#pragma unroll
      for (int j = 0; j < 8; ++j) { a0[j] = f2bf(wr[j]); a1[j] = f2bf(wr[32 + j]); }
    }
    float bi[4];
#pragma unroll
    for (int i = 0; i < 4; ++i) bi[i] = bsrc[cs * 16 + quad * 4 + i];
#pragma unroll
    for (int ps = 0; ps < 2; ++ps) {
      f32x4 acc = {bi[0], bi[1], bi[2], bi[3]};
      acc = __builtin_amdgcn_mfma_f32_16x16x32_bf16(a0, b0[ps], acc, 0, 0, 0);
      acc = __builtin_amdgcn_mfma_f32_16x16x32_bf16(a1, b1[ps], acc, 0, 0, 0);
      int idx = b * NPOS + nn + ps * 16 + L;
      if (m == 0) {
#pragma unroll
        for (int i = 0; i < 4; ++i)
          Qg[(size_t)idx * 64 + cs * 16 + quad * 4 + i] = f2bf(acc[i]);
      } else if (m == 1) {
#pragma unroll
        for (int i = 0; i < 4; ++i)
          Kg[(size_t)idx * 64 + cs * 16 + quad * 4 + i] = f2bf(acc[i] * LOG2E);
      } else {
#pragma unroll
        for (int i = 0; i < 4; ++i)
          Vgt[(size_t)(cs * 16 + quad * 4 + i) * NTOT + idx] = f2bf(acc[i]);
      }
    }
  }
}

// ---------------- Kernel B: MFMA flash attention (512 thr / 256 Q, NSPLIT=12) ----------
// grid (36, 2, NSPLIT) x 512. 256 q/block, 32 q/wave, 8 waves share one tile.
// R30 form: stores for t+1 hoisted between the two 32-key compute windows.
#define LDPK 80
#define LDP  72
__global__ __launch_bounds__(512) void k_attn(
    const short* __restrict__ Qg, const short* __restrict__ Kg, const short* __restrict__ Vgt,
    u32* __restrict__ PoT, float* __restrict__ Pl) {
  __shared__ __align__(16) short Kt[2][64 * LDPK];   // 10240 B each
  __shared__ __align__(16) short Vt[2][64 * LDP];    //  9216 B each -> 38912 total
  int b = blockIdx.y;
  int n0 = blockIdx.x * 256;
  int ks = blockIdx.z;
  int tid = threadIdx.x;
  int w = tid >> 6, lane = tid & 63;
  int L = lane & 15, quad = lane >> 4;

  bf16x8 qa[2][2];
#pragma unroll
  for (int qt = 0; qt < 2; ++qt) {
    const short* qb_ = Qg + ((size_t)(b * NPOS + n0 + w * 32 + qt * 16 + L)) * 64;
    qa[qt][0] = *(const bf16x8*)(qb_ + quad * 8);
    qa[qt][1] = *(const bf16x8*)(qb_ + 32 + quad * 8);
  }

  f32x4 o[2][4];
#pragma unroll
  for (int qt = 0; qt < 2; ++qt)
#pragma unroll
    for (int nb = 0; nb < 4; ++nb) o[qt][nb] = (f32x4){0.f, 0.f, 0.f, 0.f};
  float rl[2] = {0.f, 0.f};

  // staging maps: one i32x4 for K + one for V per thread (512 threads).
  int ck = tid & 7, rk = tid >> 3;   // K: row rk 0..63, 16B chunk ck
  int c8 = tid & 7, dr = tid >> 3;   // V: channel dr 0..63, phys keys c8*8..+7
  // V slot permutation (32-key windows, 2 per tile): phys key p=h*16+r ->
  // slot (r>>2)*8+h*4+(r&3); keys c8*8..+7 -> vslot..+3 and vslot+8..+11.
  int vslot = (c8 >> 2) * 32 + (c8 & 1) * 16 + ((c8 >> 1) & 1) * 4;
  i32x4 kr, vr;
  // load tile 0 and stage into buffer 0
  {
    int kt = ks * TILES_PER_SPLIT;
    kr = ((const i32x4*)(Kg + ((size_t)(b * NPOS + kt * 64)) * 64))[tid];
    vr = *(const i32x4*)(Vgt + (size_t)b * NPOS + kt * 64 + c8 * 8 + (size_t)dr * NTOT);
    ((i32x4*)Kt[0])[rk * 10 + ck] = kr;
    short* vrow = Vt[0] + dr * LDP + vslot;
    *(i32x2*)(vrow) = (i32x2){vr[0], vr[1]};
    *(i32x2*)(vrow + 8) = (i32x2){vr[2], vr[3]};
  }

  for (int t = 0; t < TILES_PER_SPLIT; ++t) {
    int cur = t & 1;
    // issue next-tile global loads (in flight across the barrier + compute)
    if (t + 1 < TILES_PER_SPLIT) {
      int kt = ks * TILES_PER_SPLIT + t + 1;
      kr = ((const i32x4*)(Kg + ((size_t)(b * NPOS + kt * 64)) * 64))[tid];
      vr = *(const i32x4*)(Vgt + (size_t)b * NPOS + kt * 64 + c8 * 8 + (size_t)dr * NTOT);
    }
    __syncthreads();   // buf[cur] fully staged (by prev iteration / preamble)

    const i32x4* kt4 = (const i32x4*)Kt[cur];
    const short* vt = Vt[cur];
    auto compute_win = [&](int kp) {
      u32 pw0[4], pw1[4];
#pragma unroll
      for (int h = 0; h < 2; ++h) {
        int kti = kp * 2 + h;
        bf16x8 kf0 = __builtin_bit_cast(bf16x8, kt4[(kti * 16 + L) * 10 + quad]);
        bf16x8 kf1 = __builtin_bit_cast(bf16x8, kt4[(kti * 16 + L) * 10 + 4 + quad]);
#pragma unroll
        for (int qt = 0; qt < 2; ++qt) {
          f32x4 st = {0.f, 0.f, 0.f, 0.f};
          st = __builtin_amdgcn_mfma_f32_16x16x32_bf16(kf0, qa[qt][0], st, 0, 0, 0);
          st = __builtin_amdgcn_mfma_f32_16x16x32_bf16(kf1, qa[qt][1], st, 0, 0, 0);
          float p0 = __builtin_amdgcn_exp2f(st[0]);
          float p1 = __builtin_amdgcn_exp2f(st[1]);
          float p2 = __builtin_amdgcn_exp2f(st[2]);
          float p3 = __builtin_amdgcn_exp2f(st[3]);
          rl[qt] += (p0 + p1) + (p2 + p3);
          u32 lo = __builtin_amdgcn_perm(__builtin_bit_cast(u32, p1), __builtin_bit_cast(u32, p0), 0x07060302u);
          u32 hi = __builtin_amdgcn_perm(__builtin_bit_cast(u32, p3), __builtin_bit_cast(u32, p2), 0x07060302u);
          if (qt == 0) { pw0[h * 2] = lo; pw0[h * 2 + 1] = hi; }
          else         { pw1[h * 2] = lo; pw1[h * 2 + 1] = hi; }
        }
      }
      i32x4 pq0 = {(int)pw0[0], (int)pw0[1], (int)pw0[2], (int)pw0[3]};
      i32x4 pq1 = {(int)pw1[0], (int)pw1[1], (int)pw1[2], (int)pw1[3]};
      bf16x8 pp0 = __builtin_bit_cast(bf16x8, pq0);
      bf16x8 pp1 = __builtin_bit_cast(bf16x8, pq1);
#pragma unroll
      for (int nb = 0; nb < 4; ++nb) {
        bf16x8 va8 = *(const bf16x8*)(vt + (nb * 16 + L) * LDP + kp * 32 + quad * 8);
        o[0][nb] = __builtin_amdgcn_mfma_f32_16x16x32_bf16(va8, pp0, o[0][nb], 0, 0, 0);
        o[1][nb] = __builtin_amdgcn_mfma_f32_16x16x32_bf16(va8, pp1, o[1][nb], 0, 0, 0);
      }
    };

    __builtin_amdgcn_s_setprio(1);
    compute_win(0);
    __builtin_amdgcn_s_setprio(0);

    // stage next tile into the OTHER buffer between the two compute windows:
    // the vmcnt wait for (kr,vr) overlaps kp0's compute, and the lgkm drain of
    // these stores overlaps kp1's compute instead of stalling at the barrier.
    if (t + 1 < TILES_PER_SPLIT) {
      int nxt = 1 - cur;
      ((i32x4*)Kt[nxt])[rk * 10 + ck] = kr;
      short* vrow = Vt[nxt] + dr * LDP + vslot;
      *(i32x2*)(vrow) = (i32x2){vr[0], vr[1]};
      *(i32x2*)(vrow + 8) = (i32x2){vr[2], vr[3]};
    }

    __builtin_amdgcn_s_setprio(1);
    compute_win(1);
    __builtin_amdgcn_s_setprio(0);
  }

#pragma unroll
  for (int qt = 0; qt < 2; ++qt) {
    rl[qt] += __shfl_xor(rl[qt], 16);
    rl[qt] += __shfl_xor(rl[qt], 32);
  }

#pragma unroll
  for (int qt = 0; qt < 2; ++qt) {
    int qg = b * NPOS + n0 + w * 32 + qt * 16 + L;
#pragma unroll
    for (int nb = 0; nb < 4; ++nb)
#pragma unroll
      for (int ip = 0; ip < 2; ++ip) {
        u32 pk = ((u32)(unsigned short)f2bf(o[qt][nb][2 * ip + 1]) << 16) |
                 (u32)(unsigned short)f2bf(o[qt][nb][2 * ip]);
        int d32 = nb * 8 + quad * 2 + ip;
        PoT[((size_t)(ks * 32 + d32)) * NTOT + qg] = pk;
      }
    if (quad == 0) Pl[(size_t)ks * NTOT + qg] = rl[qt];
  }
}

// ---------------- Kernel C: merge + residual + LN2 + MFMA proj_in (+X2) ----------------
// R29 form: grid (576) x 256, vectorized merge (12 i32x4 PoT + 2 f32x4 x).
__global__ __launch_bounds__(256) void k_res_ln2_proj(
    const float* __restrict__ x, const u32* __restrict__ PoT, const float* __restrict__ Pl,
    const float* __restrict__ ln2w, const float* __restrict__ ln2b,
    const float* __restrict__ piw,
    float* __restrict__ X2, float* __restrict__ Hbuf) {
  __shared__ float s1a[32 * 32], s2a[32 * 32];
  __shared__ float inva[32], mua[32], rsa[32];
  __shared__ __align__(16) short xn[32 * 72];
  int t = threadIdx.x;
  int q0 = blockIdx.x * 32;
  int b = q0 / NPOS;
  int nn = q0 % NPOS;

  // phase 0: per-position 1/l
  if (t < 32) {
    float ls = 0.f;
#pragma unroll
    for (int s = 0; s < NSPLIT; ++s) ls += Pl[(size_t)s * NTOT + q0 + t];
    inva[t] = 1.f / ls;
  }
  __syncthreads();

  int rho = t >> 3;       // PoT row 0..31 -> channels 2rho, 2rho+1
  int p4 = (t & 7) * 4;   // 4 consecutive positions
  int c0 = rho * 2;

  float aL[4] = {0.f, 0.f, 0.f, 0.f}, aH[4] = {0.f, 0.f, 0.f, 0.f};
#pragma unroll
  for (int s = 0; s < NSPLIT; ++s) {
    i32x4 v = *(const i32x4*)(PoT + (size_t)(s * 32 + rho) * NTOT + q0 + p4);
#pragma unroll
    for (int i = 0; i < 4; ++i) {
      u32 u = (u32)v[i];
      aL[i] += __builtin_bit_cast(float, u << 16);
      aH[i] += __builtin_bit_cast(float, u & 0xffff0000u);
    }
  }
  f32x4 x0 = *(const f32x4*)(x + (size_t)b * CH * NPOS + (size_t)c0 * NPOS + nn + p4);
  f32x4 x1 = *(const f32x4*)(x + (size_t)b * CH * NPOS + (size_t)(c0 + 1) * NPOS + nn + p4);
  float v0[4], v1[4];
  f32x4 ps1, ps2;
#pragma unroll
  for (int i = 0; i < 4; ++i) {
    float iv = inva[p4 + i];
    v0[i] = x0[i] + aL[i] * iv;
    v1[i] = x1[i] + aH[i] * iv;
    ps1[i] = v0[i] + v1[i];
    ps2[i] = v0[i] * v0[i] + v1[i] * v1[i];
  }
  *(f32x4*)&s1a[rho * 32 + p4] = ps1;
  *(f32x4*)&s2a[rho * 32 + p4] = ps2;
  {
    float* xo = X2 + (size_t)b * CH * NPOS + nn + p4;
    *(f32x4*)(xo + (size_t)c0 * NPOS) = (f32x4){v0[0], v0[1], v0[2], v0[3]};
    *(f32x4*)(xo + (size_t)(c0 + 1) * NPOS) = (f32x4){v1[0], v1[1], v1[2], v1[3]};
  }
  __syncthreads();
  if (t < 32) {
    float m = 0.f, m2 = 0.f;
#pragma unroll
    for (int r = 0; r < 32; ++r) { m += s1a[r * 32 + t]; m2 += s2a[r * 32 + t]; }
    m *= (1.f / 64.f);
    float var = m2 * (1.f / 64.f) - m * m;
    mua[t] = m;
    rsa[t] = rsqrtf(var + 1e-5f);
  }
  __syncthreads();
  {
    u32* xw = (u32*)xn;
    float w0 = ln2w[c0], w1 = ln2w[c0 + 1];
    float bb0 = ln2b[c0], bb1 = ln2b[c0 + 1];
#pragma unroll
    for (int i = 0; i < 4; ++i) {
      int p = p4 + i;
      float mu = mua[p], rs = rsa[p];
      float y0 = (v0[i] - mu) * rs * w0 + bb0;
      float y1 = (v1[i] - mu) * rs * w1 + bb1;
      xw[p * 36 + rho] = ((u32)(unsigned short)f2bf(y1) << 16) | (u32)(unsigned short)f2bf(y0);
    }
  }
  __syncthreads();
  int lane = t & 63;
  int L = lane & 15, quad = lane >> 4;
  int cs = t >> 6;   // warp = channel strip 0..3
  bf16x8 a0, a1;
  {
    const float* wr = piw + (cs * 16 + L) * 64 + quad * 8;
#pragma unroll
    for (int j = 0; j < 8; ++j) { a0[j] = f2bf(wr[j]); a1[j] = f2bf(wr[32 + j]); }
  }
  float* hb = Hbuf + (size_t)b * CH * NPOS + nn;
#pragma unroll
  for (int ps = 0; ps < 2; ++ps) {
    bf16x8 b0 = *(const bf16x8*)(xn + (ps * 16 + L) * 72 + quad * 8);
    bf16x8 b1 = *(const bf16x8*)(xn + (ps * 16 + L) * 72 + 32 + quad * 8);
    f32x4 acc = {0.f, 0.f, 0.f, 0.f};
    acc = __builtin_amdgcn_mfma_f32_16x16x32_bf16(a0, b0, acc, 0, 0, 0);
    acc = __builtin_amdgcn_mfma_f32_16x16x32_bf16(a1, b1, acc, 0, 0, 0);
#pragma unroll
    for (int i = 0; i < 4; ++i)
      hb[(size_t)(cs * 16 + quad * 4 + i) * NPOS + ps * 16 + L] = acc[i];
  }
}

// ---------------- Kernel D: per-patch circular conv (spatial kernel built inline) -------
// R31 form: grid (6, 64, 2) x 192 — 2 bands/block, kl shared.
#define LDB 100
__global__ __launch_bounds__(192) void k_conv(
    float* __restrict__ Hbuf, const float* __restrict__ fftw) {
  __shared__ __align__(16) float band[2][8 * LDB];
  __shared__ float kl[64];
  int c = blockIdx.y, b = blockIdx.z;
  int t = threadIdx.x;
  int g = t / 96, tt = t % 96;
  int hb = blockIdx.x * 2 + g;
  float* base = Hbuf + (size_t)(b * CH + c) * NPOS + hb * 8 * 96;
  // build spatial kernel: k_c = irfft2(hermitian-ext(w_c)) via cosine sum
  if (t < 64) {
    int dp = t >> 3, dq = t & 7;
    const float r = 0.70710678118654752440f;
    const float CO[8] = {1.f, r, 0.f, -r, -1.f, -r, 0.f, r};
    const float* wc = fftw + c * 40;
    float acc = 0.f;
#pragma unroll
    for (int u = 0; u < 8; ++u) {
#pragma unroll
      for (int v = 0; v < 8; ++v) {
        float wv = (v <= 4) ? wc[u * 5 + v] : wc[((8 - u) & 7) * 5 + (8 - v)];
        acc += wv * CO[(u * dp + v * dq) & 7];
      }
    }
    kl[t] = acc * (1.f / 64.f);
  }
  // stage band: within band g, thread tt loads floats tt*8..tt*8+7
  {
    int sr = tt / 12, sc = (tt % 12) * 8;
    f32x4 a = *(const f32x4*)(base + sr * 96 + sc);
    f32x4 d = *(const f32x4*)(base + sr * 96 + sc + 4);
    *(f32x4*)&band[g][sr * LDB + sc] = a;
    *(f32x4*)&band[g][sr * LDB + sc + 4] = d;
  }
  __syncthreads();
  int p = tt / 12, wb = tt % 12;
  float out[8] = {0.f, 0.f, 0.f, 0.f, 0.f, 0.f, 0.f, 0.f};
#pragma unroll
  for (int dp = 0; dp < 8; ++dp) {
    int rr = (p - dp) & 7;
    f32x4 a = *(const f32x4*)&band[g][rr * LDB + wb * 8];
    f32x4 d = *(const f32x4*)&band[g][rr * LDB + wb * 8 + 4];
    float v[8] = {a[0], a[1], a[2], a[3], d[0], d[1], d[2], d[3]};
    const float* krow = &kl[dp * 8];
#pragma unroll
    for (int dq = 0; dq < 8; ++dq) {
      float kv = krow[dq];
#pragma unroll
      for (int q = 0; q < 8; ++q) out[q] += kv * v[(q - dq) & 7];
    }
  }
  __syncthreads();   // all reads done before in-place overwrite
  f32x4 w0 = {out[0], out[1], out[2], out[3]};
  f32x4 w1 = {out[4], out[5], out[6], out[7]};
  *(f32x4*)(base + p * 96 + wb * 8) = w0;
  *(f32x4*)(base + p * 96 + wb * 8 + 4) = w1;
}

// ---------------- Kernel E1: dwconv3x3 + gelu-gate -> G ----------------
// R30 form: grid (18, 32) x 256, 4 pos/thread, branchless x-edges.
__global__ __launch_bounds__(256) void k_dw_gate(
    const float* __restrict__ Hbuf, const float* __restrict__ dww,
    float* __restrict__ G) {
  int cc = blockIdx.y;
  int q4 = (blockIdx.x * 256 + threadIdx.x) * 4;
  int b = q4 / NPOS, n = q4 % NPOS;
  int y = n / 96, x0 = n % 96;
  const float* h1 = Hbuf + (size_t)(b * CH + cc) * NPOS;
  const float* h2 = Hbuf + (size_t)(b * CH + cc + 32) * NPOS;
  float wd1[9], wd2[9];
#pragma unroll
  for (int ki = 0; ki < 9; ++ki) { wd1[ki] = dww[cc * 9 + ki]; wd2[ki] = dww[(cc + 32) * 9 + ki]; }
  f32x4 d1 = {0.f, 0.f, 0.f, 0.f}, d2 = {0.f, 0.f, 0.f, 0.f};
#pragma unroll
  for (int dy = -1; dy <= 1; ++dy) {
    int yy = y + dy;
    if (yy < 0 || yy >= 96) continue;
    const float* r1 = h1 + yy * 96 + x0;
    const float* r2 = h2 + yy * 96 + x0;
    f32x4 c1 = *(const f32x4*)r1;
    f32x4 c2 = *(const f32x4*)r2;
    float l1 = (x0 > 0) ? r1[-1] : 0.f;
    float l2 = (x0 > 0) ? r2[-1] : 0.f;
    float rr1 = (x0 + 4 < 96) ? r1[4] : 0.f;
    float rr2 = (x0 + 4 < 96) ? r2[4] : 0.f;
    int kb = (dy + 1) * 3;
    f32x4 L1 = {l1, c1[0], c1[1], c1[2]};
    f32x4 R1 = {c1[1], c1[2], c1[3], rr1};
    f32x4 L2 = {l2, c2[0], c2[1], c2[2]};
    f32x4 R2 = {c2[1], c2[2], c2[3], rr2};
    d1 += L1 * wd1[kb] + c1 * wd1[kb + 1] + R1 * wd1[kb + 2];
    d2 += L2 * wd2[kb] + c2 * wd2[kb + 1] + R2 * wd2[kb + 2];
  }
  f32x4 gv;
#pragma unroll
  for (int i = 0; i < 4; ++i) gv[i] = gelu_exact(d1[i]) * d2[i];
  *(f32x4*)(G + (size_t)cc * NTOT + q4) = gv;
}

// ---------------- Kernel E2: proj_out + residual ----------------
// R31 form: grid (18, 16) x 256, 4 pos/thread, f32x4 G loads.
__global__ __launch_bounds__(256) void k_proj_out(
    const float* __restrict__ G, const float* __restrict__ poww,
    const float* __restrict__ X2, float* __restrict__ out) {
  int og = blockIdx.y;
  int q4 = (blockIdx.x * 256 + threadIdx.x) * 4;
  int b = q4 / NPOS, n = q4 % NPOS;
  const float* xr = X2 + (size_t)b * CH * NPOS + n;
  float* ob = out + (size_t)b * CH * NPOS + n;
  f32x4 acc[4];
#pragma unroll
  for (int j = 0; j < 4; ++j)
    acc[j] = *(const f32x4*)(xr + (size_t)(og * 4 + j) * NPOS);
#pragma unroll
  for (int cg = 0; cg < 32; ++cg) {
    f32x4 gv = *(const f32x4*)(G + (size_t)cg * NTOT + q4);
#pragma unroll
    for (int j = 0; j < 4; ++j)
      acc[j] += poww[(og * 4 + j) * 32 + cg] * gv;
  }
#pragma unroll
  for (int j = 0; j < 4; ++j)
    *(f32x4*)(ob + (size_t)(og * 4 + j) * NPOS) = acc[j];
}

extern "C" void kernel_launch(void* const* d_in, const int* in_sizes, int n_in,
                              void* d_out, int out_size, void* d_ws, size_t ws_size,
                              hipStream_t stream) {
  const float* x    = (const float*)d_in[0];
  const float* ln1w = (const float*)d_in[1];
  const float* ln1b = (const float*)d_in[2];
  const float* ln2w = (const float*)d_in[3];
  const float* ln2b = (const float*)d_in[4];
  const float* qw   = (const float*)d_in[5];
  const float* qb   = (const float*)d_in[6];
  const float* kw   = (const float*)d_in[7];
  const float* kb   = (const float*)d_in[8];
  const float* vw   = (const float*)d_in[9];
  const float* vb   = (const float*)d_in[10];
  const float* fftw = (const float*)d_in[11];
  const float* piw  = (const float*)d_in[12];
  const float* dww  = (const float*)d_in[13];
  const float* poww = (const float*)d_in[14];

  short* Qg  = (short*)d_ws;
  short* Kg  = Qg + (size_t)NTOT * 64;
  short* Vgt = Kg + (size_t)NTOT * 64;
  u32*   PoT = (u32*)(Vgt + (size_t)NTOT * 64);
  float* Pl  = (float*)(PoT + (size_t)NSPLIT * 32 * NTOT);
  float* X2  = Pl + (size_t)NSPLIT * NTOT;
  float* Hbuf = X2 + (size_t)NTOT * 64;
  float* G   = Hbuf + (size_t)NTOT * 64;

  k_ln_qkv<<<dim3(576), 256, 0, stream>>>(x, ln1w, ln1b, qw, qb, kw, kb, vw, vb, Qg, Kg, Vgt);
  k_attn<<<dim3(36, 2, NSPLIT), 512, 0, stream>>>(Qg, Kg, Vgt, PoT, Pl);
  k_res_ln2_proj<<<dim3(576), 256, 0, stream>>>(x, PoT, Pl, ln2w, ln2b, piw, X2, Hbuf);
  k_conv<<<dim3(6, 64, 2), 192, 0, stream>>>(Hbuf, fftw);
  k_dw_gate<<<dim3(18, 32), 256, 0, stream>>>(Hbuf, dww, G);
  k_proj_out<<<dim3(18, 16), 256, 0, stream>>>(G, poww, X2, (float*)d_out);
}